// Round 4
// baseline (209.520 us; speedup 1.0000x reference)
//
#include <hip/hip_runtime.h>
#include <hip/hip_bf16.h>

#define N_   8192
#define DIM_ 512
#define DK_  128
#define DV_  512
#define L2E_  1.44269504088896f
#define CBIAS_ 0.0028169f   // +half-ulp trunc compensation in exp2 domain

typedef short short8 __attribute__((ext_vector_type(8)));
typedef float f32x4  __attribute__((ext_vector_type(4)));

__device__ __forceinline__ float fexp2(float x) { return __builtin_amdgcn_exp2f(x); }

__device__ __forceinline__ ushort f2bf(float f) {
    union { float f; unsigned u; } v; v.f = f;
    unsigned u = v.u;
    return (ushort)((u + 0x7FFFu + ((u >> 16) & 1u)) >> 16);
}

// ---- kernel 1: u1 = w_w^T a1, u2 = w_w^T a2, c1 = w_b.a1, c2 = w_b.a2 ----
__global__ void prep_kernel(const float* __restrict__ w_w, const float* __restrict__ w_b,
                            const float* __restrict__ a, float* __restrict__ u1,
                            float* __restrict__ u2, float* __restrict__ scal) {
    int d = threadIdx.x;                 // 512 threads
    float s1 = 0.f, s2 = 0.f;
    for (int k = 0; k < DK_; ++k) {
        float w = w_w[k * DIM_ + d];
        s1 += w * a[k];
        s2 += w * a[DK_ + k];
    }
    u1[d] = s1; u2[d] = s2;
    if (d == 0) { float c = 0.f; for (int k = 0; k < DK_; ++k) c += w_b[k] * a[k];        scal[0] = c; }
    if (d == 1) { float c = 0.f; for (int k = 0; k < DK_; ++k) c += w_b[k] * a[DK_ + k];  scal[1] = c; }
}

// ---- kernel 2: e_src[i], e_dst[i], and bf16 copy of x ----
__global__ __launch_bounds__(256) void e_kernel(const float* __restrict__ x,
        const float* __restrict__ u1, const float* __restrict__ u2,
        const float* __restrict__ scal, float* __restrict__ e_src, float* __restrict__ e_dst,
        ushort* __restrict__ xbf) {
    int wid = threadIdx.x >> 6, lane = threadIdx.x & 63;
    int row = blockIdx.x * 4 + wid;
    const float* xr = x + (size_t)row * DIM_;
    int d0 = lane * 8;
    f32x4 xa = *(const f32x4*)(xr + d0);
    f32x4 xb = *(const f32x4*)(xr + d0 + 4);
    f32x4 ua = *(const f32x4*)(u1 + d0);
    f32x4 ub = *(const f32x4*)(u1 + d0 + 4);
    f32x4 va = *(const f32x4*)(u2 + d0);
    f32x4 vb = *(const f32x4*)(u2 + d0 + 4);
    short8 xv;
#pragma unroll
    for (int e = 0; e < 4; ++e) { xv[e] = (short)f2bf(xa[e]); xv[e + 4] = (short)f2bf(xb[e]); }
    *(short8*)(xbf + (size_t)row * DIM_ + d0) = xv;
    float s1 = 0.f, s2 = 0.f;
#pragma unroll
    for (int e = 0; e < 4; ++e) {
        s1 += xa[e] * ua[e] + xb[e] * ub[e];
        s2 += xa[e] * va[e] + xb[e] * vb[e];
    }
    for (int off = 32; off; off >>= 1) { s1 += __shfl_xor(s1, off); s2 += __shfl_xor(s2, off); }
    if (lane == 0) {
        e_src[row] = s1 + scal[0];
        e_dst[row] = s2 + scal[1];
    }
}

// ---- kernel 3: M = max_j e_dst[j] ----
__global__ void max_kernel(const float* __restrict__ e_dst, float* __restrict__ scal) {
    __shared__ float red[256];
    int t = threadIdx.x;
    float m = -1e30f;
    for (int i = t; i < N_; i += 256) m = fmaxf(m, e_dst[i]);
    red[t] = m; __syncthreads();
    for (int s = 128; s; s >>= 1) { if (t < s) red[t] = fmaxf(red[t], red[t + s]); __syncthreads(); }
    if (t == 0) scal[2] = red[0];
}

// ---- kernel 3b: G1[j]=2^((ed-M)L2E), G2[j]=2^(0.01(ed-M)L2E) ----
__global__ __launch_bounds__(256) void g_kernel(const float* __restrict__ e_dst,
        const float* __restrict__ scal, float* __restrict__ G1, float* __restrict__ G2) {
    int j = blockIdx.x * 256 + threadIdx.x;
    float d = (e_dst[j] - scal[2]) * L2E_;
    G1[j] = fexp2(d);
    G2[j] = fexp2(0.01f * d);
}

// ---- kernel 4: vT[c][j] = bf16( x[j]. wv_w[c] + wv_b[c] ), MFMA, x from bf16 copy ----
__global__ __launch_bounds__(256) void vt_kernel(const ushort* __restrict__ xbf,
        const float* __restrict__ wv_w, const float* __restrict__ wv_b,
        ushort* __restrict__ vT) {
    int wid = threadIdx.x >> 6, lane = threadIdx.x & 63;
    int ln16 = lane & 15, kg = lane >> 4;
    int cb = blockIdx.y * 64;                 // c block (8 blocks)
    int jb = blockIdx.x * 256 + wid * 64;     // j block (32 blocks x 4 waves)
    f32x4 acc[4][4] = {};
    for (int k0 = 0; k0 < DIM_; k0 += 32) {
        int kk = k0 + kg * 8;
        short8 afr[4], bfr[4];
#pragma unroll
        for (int mg = 0; mg < 4; ++mg) {
            const float* p = wv_w + (size_t)(cb + mg * 16 + ln16) * DIM_ + kk;
            f32x4 lo = *(const f32x4*)p, hi = *(const f32x4*)(p + 4);
            short8 f;
#pragma unroll
            for (int e = 0; e < 4; ++e) { f[e] = (short)f2bf(lo[e]); f[e + 4] = (short)f2bf(hi[e]); }
            afr[mg] = f;
        }
#pragma unroll
        for (int ng = 0; ng < 4; ++ng)
            bfr[ng] = *(const short8*)(xbf + (size_t)(jb + ng * 16 + ln16) * DIM_ + kk);
#pragma unroll
        for (int mg = 0; mg < 4; ++mg)
#pragma unroll
            for (int ng = 0; ng < 4; ++ng)
                acc[mg][ng] = __builtin_amdgcn_mfma_f32_16x16x32_bf16(afr[mg], bfr[ng], acc[mg][ng], 0, 0, 0);
    }
#pragma unroll
    for (int mg = 0; mg < 4; ++mg) {
#pragma unroll
        for (int r = 0; r < 4; ++r) {
            int c_row = cb + mg * 16 + kg * 4 + r;
            float bias = wv_b[c_row];
#pragma unroll
            for (int ng = 0; ng < 4; ++ng) {
                int j_col = jb + ng * 16 + ln16;
                vT[(size_t)c_row * N_ + j_col] = f2bf(acc[mg][ng][r] + bias);
            }
        }
    }
}

// ---- kernel 5: out_partial = P @ V, P generated as max(F1*G1, F2*G2), no exp in loop ----
// A-slot: vT (128 c via 8 frags), B-slot: generated P^T (64 i via 4 frags)
__global__ __launch_bounds__(256, 2) void attn_t2_kernel(const ushort* __restrict__ vT,
        const float* __restrict__ e_src, const float* __restrict__ G1,
        const float* __restrict__ G2, const float* __restrict__ scal,
        float* __restrict__ out, float* __restrict__ wsparts, float* __restrict__ zpart,
        int jlen) {
    int wid = threadIdx.x >> 6, lane = threadIdx.x & 63;
    int ln16 = lane & 15, kg = lane >> 4;
    int bx = blockIdx.x;
    int slot = bx & 7;           // -> XCD affinity
    int cg   = slot >> 1;        // 4 c-groups of 128
    int copy = slot & 1;         // 2 i-copies per c-group
    int rest = bx >> 3;
    int ib = (rest & 15) | (copy << 4);   // 32 i-blocks of 256
    int js = rest >> 4;
    int c0 = cg * 128;
    int i0 = ib * 256 + wid * 64;

    float M = scal[2];
    float F1[4], F2[4];
#pragma unroll
    for (int ng = 0; ng < 4; ++ng) {
        float t = e_src[i0 + ng * 16 + ln16] + M;
        float m = fmaxf(t, 0.01f * t);          // analytic row max of leaky logits
        F1[ng] = fexp2((t - m) * L2E_ + CBIAS_);
        F2[ng] = fexp2((0.01f * t - m) * L2E_ + CBIAS_);
    }

    f32x4 acc[8][4] = {};
    f32x4 zc[4] = {};
    short8 onesA;
#pragma unroll
    for (int e = 0; e < 8; ++e) onesA[e] = (short)0x3F80;

    const ushort* va[8];
#pragma unroll
    for (int mg = 0; mg < 8; ++mg)
        va[mg] = vT + (size_t)(c0 + mg * 16 + ln16) * N_ + kg * 8;

    int j0 = js * jlen, j1 = j0 + jlen;
    bool do_z = (cg == 0);

#define ATTN_LOOP(DOZ)                                                                     \
    for (int jj = j0; jj < j1; jj += 32) {                                                 \
        short8 a[8];                                                                       \
        _Pragma("unroll")                                                                  \
        for (int mg = 0; mg < 8; ++mg) a[mg] = *(const short8*)(va[mg] + jj);              \
        f32x4 g1a = *(const f32x4*)(G1 + jj + kg * 8);                                     \
        f32x4 g1b = *(const f32x4*)(G1 + jj + kg * 8 + 4);                                 \
        f32x4 g2a = *(const f32x4*)(G2 + jj + kg * 8);                                     \
        f32x4 g2b = *(const f32x4*)(G2 + jj + kg * 8 + 4);                                 \
        _Pragma("unroll")                                                                  \
        for (int ng = 0; ng < 4; ++ng) {                                                   \
            f32x4 lo, hi;                                                                  \
            _Pragma("unroll")                                                              \
            for (int e = 0; e < 4; ++e) {                                                  \
                lo[e] = fmaxf(F1[ng] * g1a[e], F2[ng] * g2a[e]);                           \
                hi[e] = fmaxf(F1[ng] * g1b[e], F2[ng] * g2b[e]);                           \
            }                                                                              \
            union { short8 s; unsigned u[4]; } bb;                                         \
            bb.u[0] = __builtin_amdgcn_perm(__float_as_uint(lo[1]), __float_as_uint(lo[0]), 0x07060302u); \
            bb.u[1] = __builtin_amdgcn_perm(__float_as_uint(lo[3]), __float_as_uint(lo[2]), 0x07060302u); \
            bb.u[2] = __builtin_amdgcn_perm(__float_as_uint(hi[1]), __float_as_uint(hi[0]), 0x07060302u); \
            bb.u[3] = __builtin_amdgcn_perm(__float_as_uint(hi[3]), __float_as_uint(hi[2]), 0x07060302u); \
            if (DOZ) zc[ng] = __builtin_amdgcn_mfma_f32_16x16x32_bf16(onesA, bb.s, zc[ng], 0, 0, 0); \
            _Pragma("unroll")                                                              \
            for (int mg = 0; mg < 8; ++mg)                                                 \
                acc[mg][ng] = __builtin_amdgcn_mfma_f32_16x16x32_bf16(a[mg], bb.s, acc[mg][ng], 0, 0, 0); \
        }                                                                                  \
    }

    if (do_z) { ATTN_LOOP(true) } else { ATTN_LOOP(false) }
#undef ATTN_LOOP

    float* pp = (js == 0) ? out : (wsparts + (size_t)(js - 1) * ((size_t)N_ * DV_));
#pragma unroll
    for (int mg = 0; mg < 8; ++mg) {
        int c = c0 + mg * 16 + kg * 4;
#pragma unroll
        for (int ng = 0; ng < 4; ++ng) {
            int i = i0 + ng * 16 + ln16;
            *(f32x4*)(pp + (size_t)i * DV_ + c) = acc[mg][ng];
        }
    }
    if (do_z && kg == 0) {
#pragma unroll
        for (int ng = 0; ng < 4; ++ng)
            zpart[js * N_ + i0 + ng * 16 + ln16] = zc[ng][0];
    }
}

// ---- kernel 6: out = (sum of partials) / z ----
__global__ __launch_bounds__(256) void reduce_kernel(float* __restrict__ out,
        const float* __restrict__ wsparts, const float* __restrict__ zpart, int JS) {
    size_t flat4 = (size_t)blockIdx.x * 256 + threadIdx.x;   // over N*DV/4
    int i = (int)(flat4 >> 7);                               // 512/4 = 128 per row
    f32x4 s = ((f32x4*)out)[flat4];
    float z = zpart[i];
    for (int js = 1; js < JS; ++js) {
        s += ((const f32x4*)(wsparts + (size_t)(js - 1) * ((size_t)N_ * DV_)))[flat4];
        z += zpart[js * N_ + i];
    }
    float rz = 1.0f / z;
    ((f32x4*)out)[flat4] = s * rz;
}

extern "C" void kernel_launch(void* const* d_in, const int* in_sizes, int n_in,
                              void* d_out, int out_size, void* d_ws, size_t ws_size,
                              hipStream_t stream) {
    const float* x    = (const float*)d_in[0];
    const float* w_w  = (const float*)d_in[1];
    const float* w_b  = (const float*)d_in[2];
    const float* wv_w = (const float*)d_in[3];
    const float* wv_b = (const float*)d_in[4];
    const float* a    = (const float*)d_in[5];
    float* out = (float*)d_out;
    char* ws = (char*)d_ws;

    ushort* vT    = (ushort*)ws;                    // 0 .. 8 MiB
    float*  u1    = (float*)(ws + 8388608);
    float*  u2    = (float*)(ws + 8390656);
    float*  e_src = (float*)(ws + 8392704);
    float*  e_dst = (float*)(ws + 8425472);
    float*  G1    = (float*)(ws + 8458240);
    float*  G2    = (float*)(ws + 8491008);
    float*  scal  = (float*)(ws + 8523776);
    float*  zpart = (float*)(ws + 8523840);         // 128 KiB
    float*  wsparts = (float*)(ws + (16u << 20));   // 16 MiB.. : j-split partials
    // xbf aliases the wsparts region: vt reads it strictly before attn writes partials.
    ushort* xbf   = (ushort*)(ws + (16u << 20));    // 8 MiB (dead once vt completes)

    size_t partBytes = (size_t)N_ * DV_ * 4;        // 16 MiB
    int JS = 1;
    if (ws_size >= (16u << 20) + 3 * partBytes)      JS = 4;
    else if (ws_size >= (16u << 20) + 1 * partBytes) JS = 2;
    int jlen = N_ / JS;

    hipLaunchKernelGGL(prep_kernel, dim3(1),      dim3(512), 0, stream, w_w, w_b, a, u1, u2, scal);
    hipLaunchKernelGGL(e_kernel,    dim3(N_ / 4), dim3(256), 0, stream, x, u1, u2, scal, e_src, e_dst, xbf);
    hipLaunchKernelGGL(max_kernel,  dim3(1),      dim3(256), 0, stream, e_dst, scal);
    hipLaunchKernelGGL(g_kernel,    dim3(N_ / 256), dim3(256), 0, stream, e_dst, scal, G1, G2);
    hipLaunchKernelGGL(vt_kernel,   dim3(32, 8),  dim3(256), 0, stream, xbf, wv_w, wv_b, vT);
    hipLaunchKernelGGL(attn_t2_kernel, dim3(8 * 16 * JS), dim3(256), 0, stream,
                       vT, e_src, G1, G2, scal, out, wsparts, zpart, jlen);
    hipLaunchKernelGGL(reduce_kernel, dim3(N_ * DV_ / 4 / 256), dim3(256), 0, stream,
                       out, wsparts, zpart, JS);
}